// Round 2
// baseline (582.272 us; speedup 1.0000x reference)
//
#include <hip/hip_runtime.h>
#include <stdint.h>
#include <math.h>

#define BB 16
#define NN 100000
#define DD 25
#define CC 20
#define KK 500
#define NCAND 1024
#define THRC 0.05
#define THRN 0.5

// Exact f64 score, replicating reference op order:
// conf = sigmoid(x4); softmax max = exp(0)/sum = 1/sum; score = conf * (1/sum)
__device__ __forceinline__ double score_f64(const float* row) {
    double m = (double)row[5];
#pragma unroll
    for (int i = 1; i < CC; ++i) m = fmax(m, (double)row[5 + i]);
    double s = 0.0;
#pragma unroll
    for (int i = 0; i < CC; ++i) s += exp((double)row[5 + i] - m);
    double conf = 1.0 / (1.0 + exp(-(double)row[4]));
    return conf * (1.0 / s);
}

// Stage A: per-row f64 score -> f32-rounded key (0 if masked out)
__global__ __launch_bounds__(256) void score_kernel(const float* __restrict__ outs,
                                                    uint32_t* __restrict__ keys) {
    __shared__ float tile[256 * DD];
    long long rowBase = (long long)blockIdx.x * 256;
    const float4* src = (const float4*)(outs + rowBase * DD);
    float4* dst4 = (float4*)tile;
    for (int i = threadIdx.x; i < 1600; i += 256) dst4[i] = src[i];
    __syncthreads();
    const float* row = tile + threadIdx.x * DD;
    double sc = score_f64(row);
    uint32_t key = 0;
    if (sc > THRC) key = __float_as_uint((float)sc);  // RN is monotone
    keys[rowBase + threadIdx.x] = key;
}

// Stage B: exact top-K by f64 score, f64 NMS, outputs.
__global__ __launch_bounds__(1024) void select_nms_kernel(const float* __restrict__ outs,
                                                          const uint32_t* __restrict__ keys,
                                                          float* __restrict__ out) {
    const int b = blockIdx.x;
    const int tid = threadIdx.x;
    const uint32_t* kb = keys + (size_t)b * NN;

    __shared__ uint32_t hist[256];
    __shared__ uint32_t sh_prefix, sh_need, sh_cnt;
    __shared__ unsigned long long skey[NCAND];  // f64 score bits (desc key)
    __shared__ uint32_t sidx[NCAND];            // row index (asc tiebreak)
    __shared__ double bx[KK][4];
    __shared__ double dsc[KK];
    __shared__ int lab[KK];
    __shared__ unsigned long long sup[KK][8];
    __shared__ unsigned long long keepw[8];

    // ---- 4-pass radix select (descending) for T = 500th largest f32 key ----
    uint32_t prefix = 0;
    uint32_t need = KK;
    for (int pass = 0; pass < 4; ++pass) {
        const int shift = 24 - 8 * pass;
        if (tid < 256) hist[tid] = 0;
        __syncthreads();
        for (int i = tid; i < NN; i += 1024) {
            uint32_t key = kb[i];
            bool ok = (pass == 0) || ((key >> (shift + 8)) == prefix);
            if (ok) atomicAdd(&hist[(key >> shift) & 0xFF], 1u);
        }
        __syncthreads();
        if (tid == 0) {
            uint32_t cum = 0;
            int d = 255;
            for (; d > 0; --d) {
                uint32_t h = hist[d];
                if (cum + h >= need) break;
                cum += h;
            }
            sh_prefix = (prefix << 8) | (uint32_t)d;
            sh_need = need - cum;
        }
        __syncthreads();
        prefix = sh_prefix;
        need = sh_need;
        __syncthreads();
    }
    const uint32_t T = prefix;

    // ---- init candidate slots ----
    for (int i = tid; i < NCAND; i += 1024) {
        skey[i] = 0ULL;
        sidx[i] = 0xFFFFFFFFu;
    }
    if (tid == 0) sh_cnt = 0;
    __syncthreads();

    if (T != 0) {
        // take ALL rows with f32 key >= T (superset of f64 top-500; monotone rounding)
        for (int i = tid; i < NN; i += 1024) {
            uint32_t key = kb[i];
            if (key >= T) {
                uint32_t pos = atomicAdd(&sh_cnt, 1u);
                if (pos < NCAND) {
                    const float* row = outs + ((size_t)b * NN + i) * DD;
                    double sc = score_f64(row);
                    skey[pos] = __double_as_longlong(sc);
                    sidx[pos] = (uint32_t)i;
                }
            }
        }
    } else {
        // fewer than 500 above threshold: take all positives + lowest-index zeros
        uint32_t iprefix = 0;
        uint32_t ineed = need;
        for (int pass = 0; pass < 3; ++pass) {
            const int shift = 16 - 8 * pass;
            if (tid < 256) hist[tid] = 0;
            __syncthreads();
            for (int i = tid; i < NN; i += 1024) {
                if (kb[i] == 0) {
                    uint32_t ui = (uint32_t)i;
                    if ((ui >> (shift + 8)) == iprefix)
                        atomicAdd(&hist[(ui >> shift) & 0xFF], 1u);
                }
            }
            __syncthreads();
            if (tid == 0) {
                uint32_t cum = 0;
                int d = 0;
                for (; d < 255; ++d) {
                    uint32_t h = hist[d];
                    if (cum + h >= ineed) break;
                    cum += h;
                }
                sh_prefix = (iprefix << 8) | (uint32_t)d;
                sh_need = ineed - cum;
            }
            __syncthreads();
            iprefix = sh_prefix;
            ineed = sh_need;
            __syncthreads();
        }
        const uint32_t Istar = iprefix;
        for (int i = tid; i < NN; i += 1024) {
            uint32_t key = kb[i];
            bool sel = (key > 0) || ((uint32_t)i <= Istar);
            if (sel) {
                uint32_t pos = atomicAdd(&sh_cnt, 1u);
                if (pos < NCAND) {
                    if (key > 0) {
                        const float* row = outs + ((size_t)b * NN + i) * DD;
                        skey[pos] = __double_as_longlong(score_f64(row));
                    } else {
                        skey[pos] = 0ULL;  // masked score = 0.0
                    }
                    sidx[pos] = (uint32_t)i;
                }
            }
        }
    }
    __syncthreads();

    // ---- bitonic sort NCAND by (skey desc, idx asc); sentinels last ----
    for (int k2 = 2; k2 <= NCAND; k2 <<= 1) {
        for (int j = k2 >> 1; j > 0; j >>= 1) {
            int i = tid;
            int ixj = i ^ j;
            if (ixj > i) {
                unsigned long long ka = skey[i], kc = skey[ixj];
                uint32_t ia = sidx[i], ic = sidx[ixj];
                bool a_gt_c = (ka > kc) || (ka == kc && ia < ic);
                bool up = ((i & k2) == 0);
                // ascending run wants "greater first" for descending overall
                bool sw = up ? (!a_gt_c && !(ka == kc && ia == ic)) : a_gt_c;
                if (sw) {
                    skey[i] = kc; sidx[i] = ic;
                    skey[ixj] = ka; sidx[ixj] = ia;
                }
            }
            __syncthreads();
        }
    }

    // ---- decode first KK candidates (f64) ----
    for (int i = tid; i < KK; i += 1024) {
        uint32_t idx = sidx[i];
        const float* row = outs + ((size_t)b * NN + idx) * DD;
        double cx = 1.0 / (1.0 + exp(-(double)row[0]));
        double cy = 1.0 / (1.0 + exp(-(double)row[1]));
        double w = 1.0 / (1.0 + exp(-(double)row[2]));
        double h = 1.0 / (1.0 + exp(-(double)row[3]));
        bx[i][0] = cx - 0.5 * w;
        bx[i][1] = cy - 0.5 * h;
        bx[i][2] = cx + 0.5 * w;
        bx[i][3] = cy + 0.5 * h;
        float mm = row[5];
        int am = 0;
#pragma unroll
        for (int c = 1; c < CC; ++c) {
            float v = row[5 + c];
            if (v > mm) { mm = v; am = c; }
        }
        lab[i] = am;
        dsc[i] = __longlong_as_double((long long)skey[i]);
    }
    __syncthreads();

    // ---- suppression bitmask (f64 IoU) ----
    for (int t = tid; t < KK * 8; t += 1024) {
        int i = t >> 3;
        int w = t & 7;
        double l1 = bx[i][0], t1 = bx[i][1], r1 = bx[i][2], d1 = bx[i][3];
        double a1 = fmax(r1 - l1, 0.0) * fmax(d1 - t1, 0.0);
        int li = lab[i];
        unsigned long long word = 0;
        int j0 = w * 64;
        int jend = (j0 + 64 < KK) ? 64 : (KK - j0);
        for (int jj = 0; jj < jend; ++jj) {
            int j = j0 + jj;
            if (lab[j] != li) continue;
            double l2 = bx[j][0], t2 = bx[j][1], r2 = bx[j][2], d2 = bx[j][3];
            double iw = fmax(fmin(r1, r2) - fmax(l1, l2), 0.0);
            double ih = fmax(fmin(d1, d2) - fmax(t1, t2), 0.0);
            double inter = iw * ih;
            double a2 = fmax(r2 - l2, 0.0) * fmax(d2 - t2, 0.0);
            double uni = a1 + a2 - inter;
            double iou = inter / fmax(uni, 1e-9);
            if (iou > THRN) word |= (1ULL << jj);
        }
        sup[i][w] = word;
    }
    __syncthreads();

    // ---- serial greedy NMS ----
    if (tid == 0) {
        unsigned long long kw[8] = {0, 0, 0, 0, 0, 0, 0, 0};
        for (int i = 0; i < KK; ++i) {
            unsigned long long s0 = 0;
#pragma unroll
            for (int w = 0; w < 8; ++w) s0 |= (sup[i][w] & kw[w]);
            bool valid = dsc[i] > THRC;  // masked rows have dsc == 0.0
            bool keep = valid && (s0 == 0ULL);
            if (keep) kw[i >> 6] |= (1ULL << (i & 63));
        }
#pragma unroll
        for (int w = 0; w < 8; ++w) keepw[w] = kw[w];
    }
    __syncthreads();

    // ---- outputs: [ids | boxes | labels | scores] flat f32 concat ----
    float* out_ids = out;
    float* out_boxes = out + BB * KK;
    float* out_labels = out + BB * KK * 5;
    float* out_scores = out + BB * KK * 6;
    for (int i = tid; i < KK; i += 1024) {
        bool keep = (keepw[i >> 6] >> (i & 63)) & 1ULL;
        out_ids[b * KK + i] = (float)b;
        float* bo = out_boxes + ((size_t)b * KK + i) * 4;
        bo[0] = (float)bx[i][0];
        bo[1] = (float)bx[i][1];
        bo[2] = (float)bx[i][2];
        bo[3] = (float)bx[i][3];
        out_labels[b * KK + i] = keep ? (float)lab[i] : -1.0f;
        out_scores[b * KK + i] = keep ? (float)dsc[i] : 0.0f;
    }
}

extern "C" void kernel_launch(void* const* d_in, const int* in_sizes, int n_in,
                              void* d_out, int out_size, void* d_ws, size_t ws_size,
                              hipStream_t stream) {
    const float* outs = (const float*)d_in[0];
    float* out = (float*)d_out;
    uint32_t* keys = (uint32_t*)d_ws;  // BB*NN*4 = 6.4 MB

    score_kernel<<<(BB * NN) / 256, 256, 0, stream>>>(outs, keys);
    select_nms_kernel<<<BB, 1024, 0, stream>>>(outs, keys, out);
}

// Round 3
// 507.498 us; speedup vs baseline: 1.1473x; 1.1473x over previous
//
#include <hip/hip_runtime.h>
#include <stdint.h>
#include <math.h>

#define BB 16
#define NN 100000
#define DD 25
#define CC 20
#define KK 500
#define NCAND 1024
#define NWAVE 16
#define HPAD 257
#define THRC 0.05
#define THRN 0.5

// Exact f64 score, replicating reference op order.
__device__ __forceinline__ double score_f64(const float* row) {
    double m = (double)row[5];
#pragma unroll
    for (int i = 1; i < CC; ++i) m = fmax(m, (double)row[5 + i]);
    double s = 0.0;
#pragma unroll
    for (int i = 0; i < CC; ++i) s += exp((double)row[5 + i] - m);
    double conf = 1.0 / (1.0 + exp(-(double)row[4]));
    return conf * (1.0 / s);
}

// Stage A: per-row f64 score -> f32-rounded key (0 if masked out)
__global__ __launch_bounds__(256) void score_kernel(const float* __restrict__ outs,
                                                    uint32_t* __restrict__ keys) {
    __shared__ float tile[256 * DD];
    long long rowBase = (long long)blockIdx.x * 256;
    const float4* src = (const float4*)(outs + rowBase * DD);
    float4* dst4 = (float4*)tile;
    for (int i = threadIdx.x; i < 1600; i += 256) dst4[i] = src[i];
    __syncthreads();
    const float* row = tile + threadIdx.x * DD;
    double sc = score_f64(row);
    uint32_t key = 0;
    if (sc > THRC) key = __float_as_uint((float)sc);  // RN is monotone
    keys[rowBase + threadIdx.x] = key;
}

// Stage B: exact top-K by f64 score, f64 NMS, outputs.
__global__ __launch_bounds__(1024) void select_nms_kernel(const float* __restrict__ outs,
                                                          const uint32_t* __restrict__ keys,
                                                          float* __restrict__ out) {
    const int b = blockIdx.x;
    const int tid = threadIdx.x;
    const int wave = tid >> 6;
    const uint32_t* kb = keys + (size_t)b * NN;

    __shared__ uint32_t whist[NWAVE * HPAD];  // per-wave padded histograms
    __shared__ uint32_t hist[256];            // tie-break path only
    __shared__ uint32_t sfx[256];
    __shared__ uint32_t sh_prefix, sh_need, sh_cnt;
    __shared__ unsigned long long skey[NCAND];
    __shared__ uint32_t sidx[NCAND];
    __shared__ double bx[KK][4];
    __shared__ double dsc[KK];
    __shared__ int lab[KK];
    __shared__ unsigned long long sup[KK][8];
    __shared__ unsigned long long keepw[8];

    // ---- 4-pass radix select (descending) for T = 500th largest f32 key ----
    uint32_t prefix = 0;
    uint32_t need = KK;
    for (int pass = 0; pass < 4; ++pass) {
        const int shift = 24 - 8 * pass;
        for (int i = tid; i < NWAVE * HPAD; i += 1024) whist[i] = 0;
        __syncthreads();
        for (int i = tid; i < NN; i += 1024) {
            uint32_t key = kb[i];
            bool ok = (pass == 0) || ((key >> (shift + 8)) == prefix);
            if (ok) atomicAdd(&whist[wave * HPAD + ((key >> shift) & 0xFF)], 1u);
        }
        __syncthreads();
        if (tid < 256) {
            uint32_t s = 0;
#pragma unroll
            for (int w = 0; w < NWAVE; ++w) s += whist[w * HPAD + tid];
            sfx[tid] = s;
        }
        __syncthreads();
        // suffix scan: sfx[d] = sum_{d'>=d}
        for (int off = 1; off < 256; off <<= 1) {
            uint32_t v = 0;
            if (tid < 256 && tid + off < 256) v = sfx[tid + off];
            __syncthreads();
            if (tid < 256) sfx[tid] += v;
            __syncthreads();
        }
        if (tid < 256) {
            uint32_t down = (tid == 255) ? 0u : sfx[tid + 1];
            if (down < need && sfx[tid] >= need) {
                sh_prefix = (prefix << 8) | (uint32_t)tid;
                sh_need = need - down;
            }
        }
        __syncthreads();
        prefix = sh_prefix;
        need = sh_need;
        __syncthreads();
    }
    const uint32_t T = prefix;

    // ---- init candidate slots ----
    for (int i = tid; i < NCAND; i += 1024) {
        skey[i] = 0ULL;
        sidx[i] = 0xFFFFFFFFu;
    }
    if (tid == 0) sh_cnt = 0;
    __syncthreads();

    if (T != 0) {
        // ALL rows with f32 key >= T (superset of f64 top-500; RN monotone)
        for (int i = tid; i < NN; i += 1024) {
            uint32_t key = kb[i];
            if (key >= T) {
                uint32_t pos = atomicAdd(&sh_cnt, 1u);
                if (pos < NCAND) {
                    const float* row = outs + ((size_t)b * NN + i) * DD;
                    skey[pos] = __double_as_longlong(score_f64(row));
                    sidx[pos] = (uint32_t)i;
                }
            }
        }
    } else {
        // fewer than 500 above threshold: all positives + lowest-index zeros
        uint32_t iprefix = 0;
        uint32_t ineed = need;
        for (int pass = 0; pass < 3; ++pass) {
            const int shift = 16 - 8 * pass;
            if (tid < 256) hist[tid] = 0;
            __syncthreads();
            for (int i = tid; i < NN; i += 1024) {
                if (kb[i] == 0) {
                    uint32_t ui = (uint32_t)i;
                    if ((ui >> (shift + 8)) == iprefix)
                        atomicAdd(&hist[(ui >> shift) & 0xFF], 1u);
                }
            }
            __syncthreads();
            if (tid == 0) {
                uint32_t cum = 0;
                int d = 0;
                for (; d < 255; ++d) {
                    uint32_t h = hist[d];
                    if (cum + h >= ineed) break;
                    cum += h;
                }
                sh_prefix = (iprefix << 8) | (uint32_t)d;
                sh_need = ineed - cum;
            }
            __syncthreads();
            iprefix = sh_prefix;
            ineed = sh_need;
            __syncthreads();
        }
        const uint32_t Istar = iprefix;
        for (int i = tid; i < NN; i += 1024) {
            uint32_t key = kb[i];
            bool sel = (key > 0) || ((uint32_t)i <= Istar);
            if (sel) {
                uint32_t pos = atomicAdd(&sh_cnt, 1u);
                if (pos < NCAND) {
                    if (key > 0) {
                        const float* row = outs + ((size_t)b * NN + i) * DD;
                        skey[pos] = __double_as_longlong(score_f64(row));
                    } else {
                        skey[pos] = 0ULL;
                    }
                    sidx[pos] = (uint32_t)i;
                }
            }
        }
    }
    __syncthreads();

    // ---- bitonic sort NCAND by (skey desc, idx asc); sentinels last ----
    for (int k2 = 2; k2 <= NCAND; k2 <<= 1) {
        for (int j = k2 >> 1; j > 0; j >>= 1) {
            int i = tid;
            int ixj = i ^ j;
            if (ixj > i) {
                unsigned long long ka = skey[i], kc = skey[ixj];
                uint32_t ia = sidx[i], ic = sidx[ixj];
                bool a_gt_c = (ka > kc) || (ka == kc && ia < ic);
                bool eq = (ka == kc) && (ia == ic);
                bool up = ((i & k2) == 0);
                bool sw = up ? (!a_gt_c && !eq) : a_gt_c;
                if (sw) {
                    skey[i] = kc; sidx[i] = ic;
                    skey[ixj] = ka; sidx[ixj] = ia;
                }
            }
            __syncthreads();
        }
    }

    // ---- decode first KK candidates (f64) ----
    for (int i = tid; i < KK; i += 1024) {
        uint32_t idx = sidx[i];
        const float* row = outs + ((size_t)b * NN + idx) * DD;
        double cx = 1.0 / (1.0 + exp(-(double)row[0]));
        double cy = 1.0 / (1.0 + exp(-(double)row[1]));
        double w = 1.0 / (1.0 + exp(-(double)row[2]));
        double h = 1.0 / (1.0 + exp(-(double)row[3]));
        bx[i][0] = cx - 0.5 * w;
        bx[i][1] = cy - 0.5 * h;
        bx[i][2] = cx + 0.5 * w;
        bx[i][3] = cy + 0.5 * h;
        float mm = row[5];
        int am = 0;
#pragma unroll
        for (int c = 1; c < CC; ++c) {
            float v = row[5 + c];
            if (v > mm) { mm = v; am = c; }
        }
        lab[i] = am;
        dsc[i] = __longlong_as_double((long long)skey[i]);
    }
    __syncthreads();

    // ---- suppression bitmask (f64 IoU) ----
    for (int t = tid; t < KK * 8; t += 1024) {
        int i = t >> 3;
        int w = t & 7;
        double l1 = bx[i][0], t1 = bx[i][1], r1 = bx[i][2], d1 = bx[i][3];
        double a1 = fmax(r1 - l1, 0.0) * fmax(d1 - t1, 0.0);
        int li = lab[i];
        unsigned long long word = 0;
        int j0 = w * 64;
        int jend = (j0 + 64 < KK) ? 64 : (KK - j0);
        for (int jj = 0; jj < jend; ++jj) {
            int j = j0 + jj;
            if (lab[j] != li) continue;
            double l2 = bx[j][0], t2 = bx[j][1], r2 = bx[j][2], d2 = bx[j][3];
            double iw = fmax(fmin(r1, r2) - fmax(l1, l2), 0.0);
            double ih = fmax(fmin(d1, d2) - fmax(t1, t2), 0.0);
            double inter = iw * ih;
            double a2 = fmax(r2 - l2, 0.0) * fmax(d2 - t2, 0.0);
            double uni = a1 + a2 - inter;
            double iou = inter / fmax(uni, 1e-9);
            if (iou > THRN) word |= (1ULL << jj);
        }
        sup[i][w] = word;
    }
    __syncthreads();

    // ---- wave-parallel greedy NMS: 8 chunks of 64 rows, shfl-serial inside ----
    if (tid < 64) {
        const int lane = tid;
        unsigned long long kept[8];
#pragma unroll
        for (int w = 0; w < 8; ++w) kept[w] = 0ULL;
#pragma unroll
        for (int c = 0; c < 8; ++c) {
            int i = c * 64 + lane;
            unsigned long long sprev = 0ULL;
            unsigned long long myw = 0ULL;
            bool vi = false;
            if (i < KK) {
#pragma unroll
                for (int w = 0; w < 8; ++w)
                    if (w < c) sprev |= sup[i][w] & kept[w];
                myw = sup[i][c];
                vi = dsc[i] > THRC;
            }
            unsigned long long ck = 0ULL;
            for (int j = 0; j < 64; ++j) {
                int myk = (vi && sprev == 0ULL && (myw & ck) == 0ULL) ? 1 : 0;
                int kj = __shfl(myk, j);
                if (kj) ck |= (1ULL << j);
            }
            kept[c] = ck;
        }
        if (lane == 0) {
#pragma unroll
            for (int w = 0; w < 8; ++w) keepw[w] = kept[w];
        }
    }
    __syncthreads();

    // ---- outputs: [ids | boxes | labels | scores] flat f32 concat ----
    float* out_ids = out;
    float* out_boxes = out + BB * KK;
    float* out_labels = out + BB * KK * 5;
    float* out_scores = out + BB * KK * 6;
    for (int i = tid; i < KK; i += 1024) {
        bool keep = (keepw[i >> 6] >> (i & 63)) & 1ULL;
        out_ids[b * KK + i] = (float)b;
        float* bo = out_boxes + ((size_t)b * KK + i) * 4;
        bo[0] = (float)bx[i][0];
        bo[1] = (float)bx[i][1];
        bo[2] = (float)bx[i][2];
        bo[3] = (float)bx[i][3];
        out_labels[b * KK + i] = keep ? (float)lab[i] : -1.0f;
        out_scores[b * KK + i] = keep ? (float)dsc[i] : 0.0f;
    }
}

extern "C" void kernel_launch(void* const* d_in, const int* in_sizes, int n_in,
                              void* d_out, int out_size, void* d_ws, size_t ws_size,
                              hipStream_t stream) {
    const float* outs = (const float*)d_in[0];
    float* out = (float*)d_out;
    uint32_t* keys = (uint32_t*)d_ws;  // BB*NN*4 = 6.4 MB

    score_kernel<<<(BB * NN) / 256, 256, 0, stream>>>(outs, keys);
    select_nms_kernel<<<BB, 1024, 0, stream>>>(outs, keys, out);
}

// Round 4
// 301.730 us; speedup vs baseline: 1.9298x; 1.6820x over previous
//
#include <hip/hip_runtime.h>
#include <stdint.h>
#include <math.h>

#define BB 16
#define NN 100000
#define NQ (NN / 4)
#define DD 25
#define CC 20
#define KK 500
#define NCAND 1024
#define NWAVE 16
#define HPAD 257
#define THRC 0.05
#define THRN 0.5

// Exact f64 score, replicating reference op order.
__device__ __forceinline__ double score_f64(const float* row) {
    double m = (double)row[5];
#pragma unroll
    for (int i = 1; i < CC; ++i) m = fmax(m, (double)row[5 + i]);
    double s = 0.0;
#pragma unroll
    for (int i = 0; i < CC; ++i) s += exp((double)row[5 + i] - m);
    double conf = 1.0 / (1.0 + exp(-(double)row[4]));
    return conf * (1.0 / s);
}

// Stage A: per-row f64 score -> f32 key + f64 score bits (0 if masked out)
__global__ __launch_bounds__(256) void score_kernel(const float* __restrict__ outs,
                                                    uint32_t* __restrict__ keys,
                                                    unsigned long long* __restrict__ sc64) {
    __shared__ float tile[256 * DD];
    long long rowBase = (long long)blockIdx.x * 256;
    const float4* src = (const float4*)(outs + rowBase * DD);
    float4* dst4 = (float4*)tile;
    for (int i = threadIdx.x; i < 1600; i += 256) dst4[i] = src[i];
    __syncthreads();
    const float* row = tile + threadIdx.x * DD;
    double sc = score_f64(row);
    uint32_t key = 0;
    unsigned long long s = 0ULL;
    if (sc > THRC) {
        key = __float_as_uint((float)sc);  // RN is monotone
        s = (unsigned long long)__double_as_longlong(sc);
    }
    keys[rowBase + threadIdx.x] = key;
    sc64[rowBase + threadIdx.x] = s;
}

// Stage B: exact top-K by f64 score, f64 NMS, outputs.
__global__ __launch_bounds__(1024) void select_nms_kernel(const float* __restrict__ outs,
                                                          const uint32_t* __restrict__ keys,
                                                          const unsigned long long* __restrict__ sc,
                                                          float* __restrict__ out) {
    const int b = blockIdx.x;
    const int tid = threadIdx.x;
    const int wave = tid >> 6;
    const int lane = tid & 63;
    const uint32_t* kb = keys + (size_t)b * NN;
    const uint4* kb4 = (const uint4*)kb;
    const unsigned long long* sb = sc + (size_t)b * NN;

    __shared__ uint32_t whist[NWAVE * HPAD];
    __shared__ uint32_t hist[256];  // tie-break path only
    __shared__ uint32_t sfx[256];
    __shared__ uint32_t sh_prefix, sh_need, sh_cnt;
    __shared__ unsigned long long skey[NCAND];
    __shared__ uint32_t sidx[NCAND];
    __shared__ double bxl[KK], bxt[KK], bxr[KK], bxd[KK];
    __shared__ double dsc[KK];
    __shared__ int lab[KK];
    __shared__ unsigned long long sup[KK][8];
    __shared__ unsigned long long keepw[8];

    // ---- 4-pass radix select (descending) for T = 500th largest f32 key ----
    uint32_t prefix = 0;
    uint32_t need = KK;
    for (int pass = 0; pass < 4; ++pass) {
        const int shift = 24 - 8 * pass;
        for (int i = tid; i < NWAVE * HPAD; i += 1024) whist[i] = 0;
        __syncthreads();
        for (int q = tid; q < NQ; q += 1024) {
            uint4 k4 = kb4[q];
            uint32_t kk4[4] = {k4.x, k4.y, k4.z, k4.w};
#pragma unroll
            for (int c = 0; c < 4; ++c) {
                uint32_t key = kk4[c];
                if (key != 0) {  // zeros counted implicitly via sfx[0]<need fallback
                    bool ok = (pass == 0) || ((key >> (shift + 8)) == prefix);
                    if (ok) atomicAdd(&whist[wave * HPAD + ((key >> shift) & 0xFF)], 1u);
                }
            }
        }
        __syncthreads();
        if (tid < 256) {
            uint32_t s = 0;
#pragma unroll
            for (int w = 0; w < NWAVE; ++w) s += whist[w * HPAD + tid];
            sfx[tid] = s;
        }
        __syncthreads();
        // suffix scan: sfx[d] = sum_{d'>=d}
        for (int off = 1; off < 256; off <<= 1) {
            uint32_t v = 0;
            if (tid < 256 && tid + off < 256) v = sfx[tid + off];
            __syncthreads();
            if (tid < 256) sfx[tid] += v;
            __syncthreads();
        }
        if (tid < 256) {
            uint32_t down = (tid == 255) ? 0u : sfx[tid + 1];
            if (down < need && sfx[tid] >= need) {
                sh_prefix = (prefix << 8) | (uint32_t)tid;
                sh_need = need - down;
            }
        }
        // all counted keys < need -> digit 0 (zeros live there; they were skipped)
        if (tid == 0 && sfx[0] < need) {
            sh_prefix = (prefix << 8);
            sh_need = need - sfx[1];
        }
        __syncthreads();
        prefix = sh_prefix;
        need = sh_need;
        __syncthreads();
    }
    const uint32_t T = prefix;

    // ---- init candidate slots ----
    for (int i = tid; i < NCAND; i += 1024) {
        skey[i] = 0ULL;
        sidx[i] = 0xFFFFFFFFu;
    }
    if (tid == 0) sh_cnt = 0;
    __syncthreads();

    if (T != 0) {
        // ALL rows with f32 key >= T (superset of f64 top-500; RN monotone)
        for (int q = tid; q < NQ; q += 1024) {
            uint4 k4 = kb4[q];
            uint32_t kk4[4] = {k4.x, k4.y, k4.z, k4.w};
#pragma unroll
            for (int c = 0; c < 4; ++c) {
                if (kk4[c] >= T) {
                    int i = 4 * q + c;
                    uint32_t pos = atomicAdd(&sh_cnt, 1u);
                    if (pos < NCAND) {
                        skey[pos] = sb[i];  // exact f64 score bits from stage A
                        sidx[pos] = (uint32_t)i;
                    }
                }
            }
        }
    } else {
        // fewer than 500 above threshold: all positives + lowest-index zeros
        uint32_t iprefix = 0;
        uint32_t ineed = need;
        for (int pass = 0; pass < 3; ++pass) {
            const int shift = 16 - 8 * pass;
            if (tid < 256) hist[tid] = 0;
            __syncthreads();
            for (int i = tid; i < NN; i += 1024) {
                if (kb[i] == 0) {
                    uint32_t ui = (uint32_t)i;
                    if ((ui >> (shift + 8)) == iprefix)
                        atomicAdd(&hist[(ui >> shift) & 0xFF], 1u);
                }
            }
            __syncthreads();
            if (tid == 0) {
                uint32_t cum = 0;
                int d = 0;
                for (; d < 255; ++d) {
                    uint32_t h = hist[d];
                    if (cum + h >= ineed) break;
                    cum += h;
                }
                sh_prefix = (iprefix << 8) | (uint32_t)d;
                sh_need = ineed - cum;
            }
            __syncthreads();
            iprefix = sh_prefix;
            ineed = sh_need;
            __syncthreads();
        }
        const uint32_t Istar = iprefix;
        for (int i = tid; i < NN; i += 1024) {
            uint32_t key = kb[i];
            bool sel = (key > 0) || ((uint32_t)i <= Istar);
            if (sel) {
                uint32_t pos = atomicAdd(&sh_cnt, 1u);
                if (pos < NCAND) {
                    skey[pos] = (key > 0) ? sb[i] : 0ULL;
                    sidx[pos] = (uint32_t)i;
                }
            }
        }
    }
    __syncthreads();

    // ---- bitonic sort NCAND by (skey desc, idx asc); sentinels last ----
    for (int k2 = 2; k2 <= NCAND; k2 <<= 1) {
        for (int j = k2 >> 1; j > 0; j >>= 1) {
            int i = tid;
            int ixj = i ^ j;
            if (ixj > i) {
                unsigned long long ka = skey[i], kc = skey[ixj];
                uint32_t ia = sidx[i], ic = sidx[ixj];
                bool a_gt_c = (ka > kc) || (ka == kc && ia < ic);
                bool eq = (ka == kc) && (ia == ic);
                bool up = ((i & k2) == 0);
                bool sw = up ? (!a_gt_c && !eq) : a_gt_c;
                if (sw) {
                    skey[i] = kc; sidx[i] = ic;
                    skey[ixj] = ka; sidx[ixj] = ia;
                }
            }
            __syncthreads();
        }
    }

    // ---- decode first KK candidates (f64) ----
    for (int i = tid; i < KK; i += 1024) {
        uint32_t idx = sidx[i];
        const float* row = outs + ((size_t)b * NN + idx) * DD;
        double cx = 1.0 / (1.0 + exp(-(double)row[0]));
        double cy = 1.0 / (1.0 + exp(-(double)row[1]));
        double w = 1.0 / (1.0 + exp(-(double)row[2]));
        double h = 1.0 / (1.0 + exp(-(double)row[3]));
        bxl[i] = cx - 0.5 * w;
        bxt[i] = cy - 0.5 * h;
        bxr[i] = cx + 0.5 * w;
        bxd[i] = cy + 0.5 * h;
        float mm = row[5];
        int am = 0;
#pragma unroll
        for (int c = 1; c < CC; ++c) {
            float v = row[5 + c];
            if (v > mm) { mm = v; am = c; }
        }
        lab[i] = am;
        dsc[i] = __longlong_as_double((long long)skey[i]);
    }
    __syncthreads();

    // ---- suppression bitmask, transposed: lane l handles column j = w*64+l ----
    for (int p = wave; p < KK * 8; p += NWAVE) {
        int i = p >> 3;
        int w = p & 7;
        int j = w * 64 + lane;
        bool sbit = false;
        if (j < KK && lab[j] == lab[i]) {
            double l1 = bxl[i], t1 = bxt[i], r1 = bxr[i], d1 = bxd[i];  // broadcast
            double a1 = fmax(r1 - l1, 0.0) * fmax(d1 - t1, 0.0);
            double l2 = bxl[j], t2 = bxt[j], r2 = bxr[j], d2 = bxd[j];  // stride-8B
            double iw = fmax(fmin(r1, r2) - fmax(l1, l2), 0.0);
            double ih = fmax(fmin(d1, d2) - fmax(t1, t2), 0.0);
            double inter = iw * ih;
            double a2 = fmax(r2 - l2, 0.0) * fmax(d2 - t2, 0.0);
            double uni = a1 + a2 - inter;
            double iou = inter / fmax(uni, 1e-9);
            sbit = iou > THRN;
        }
        unsigned long long word = __ballot(sbit);
        if (lane == 0) sup[i][w] = word;
    }
    __syncthreads();

    // ---- wave-parallel greedy NMS: 8 chunks of 64 rows, shfl-serial inside ----
    if (tid < 64) {
        unsigned long long kept[8];
#pragma unroll
        for (int w = 0; w < 8; ++w) kept[w] = 0ULL;
#pragma unroll
        for (int c = 0; c < 8; ++c) {
            int i = c * 64 + lane;
            unsigned long long sprev = 0ULL;
            unsigned long long myw = 0ULL;
            bool vi = false;
            if (i < KK) {
#pragma unroll
                for (int w = 0; w < 8; ++w)
                    if (w < c) sprev |= sup[i][w] & kept[w];
                myw = sup[i][c];
                vi = dsc[i] > THRC;
            }
            unsigned long long ck = 0ULL;
            for (int j = 0; j < 64; ++j) {
                int myk = (vi && sprev == 0ULL && (myw & ck) == 0ULL) ? 1 : 0;
                int kj = __shfl(myk, j);
                if (kj) ck |= (1ULL << j);
            }
            kept[c] = ck;
        }
        if (lane == 0) {
#pragma unroll
            for (int w = 0; w < 8; ++w) keepw[w] = kept[w];
        }
    }
    __syncthreads();

    // ---- outputs: [ids | boxes | labels | scores] flat f32 concat ----
    float* out_ids = out;
    float* out_boxes = out + BB * KK;
    float* out_labels = out + BB * KK * 5;
    float* out_scores = out + BB * KK * 6;
    for (int i = tid; i < KK; i += 1024) {
        bool keep = (keepw[i >> 6] >> (i & 63)) & 1ULL;
        out_ids[b * KK + i] = (float)b;
        float* bo = out_boxes + ((size_t)b * KK + i) * 4;
        bo[0] = (float)bxl[i];
        bo[1] = (float)bxt[i];
        bo[2] = (float)bxr[i];
        bo[3] = (float)bxd[i];
        out_labels[b * KK + i] = keep ? (float)lab[i] : -1.0f;
        out_scores[b * KK + i] = keep ? (float)dsc[i] : 0.0f;
    }
}

extern "C" void kernel_launch(void* const* d_in, const int* in_sizes, int n_in,
                              void* d_out, int out_size, void* d_ws, size_t ws_size,
                              hipStream_t stream) {
    const float* outs = (const float*)d_in[0];
    float* out = (float*)d_out;
    uint32_t* keys = (uint32_t*)d_ws;                                    // 6.4 MB
    unsigned long long* sc64 = (unsigned long long*)((char*)d_ws + (size_t)BB * NN * 4);  // 12.8 MB

    score_kernel<<<(BB * NN) / 256, 256, 0, stream>>>(outs, keys, sc64);
    select_nms_kernel<<<BB, 1024, 0, stream>>>(outs, keys, sc64, out);
}